// Round 7
// baseline (273.236 us; speedup 1.0000x reference)
//
#include <hip/hip_runtime.h>
#include <hip/hip_bf16.h>
#include <cstdint>
#include <cstddef>

typedef __attribute__((ext_vector_type(8))) short bf16x8;    // 8 bf16 = 4 VGPRs
typedef __attribute__((ext_vector_type(4))) float f32x4;
typedef __attribute__((ext_vector_type(16))) float f32x16;

#define MFMA16(a, b, c) __builtin_amdgcn_mfma_f32_16x16x32_bf16((a), (b), (c), 0, 0, 0)
#define MFMA32(a, b, c) __builtin_amdgcn_mfma_f32_32x32x16_bf16((a), (b), (c), 0, 0, 0)

constexpr int Bz = 4, S = 2048, E = 1024, H = 16, Dh = 64;
constexpr size_t BSE = (size_t)Bz * S * E;   // 8388608

__device__ __forceinline__ unsigned short f2bf(float f) {
    uint32_t u = __builtin_bit_cast(uint32_t, f);
    u += 0x7FFFu + ((u >> 16) & 1u);   // round-to-nearest-even
    return (unsigned short)(u >> 16);
}

__device__ __forceinline__ float exp2_fast(float x) {
#if __has_builtin(__builtin_amdgcn_exp2f)
    return __builtin_amdgcn_exp2f(x);
#else
    return exp2f(x);
#endif
}

// pack two floats to packed bf16 (round-half-up): 2 adds + 1 v_perm
__device__ __forceinline__ uint32_t pack_bf16(float a, float b) {
    uint32_t ua = __builtin_bit_cast(uint32_t, a) + 0x8000u;
    uint32_t ub = __builtin_bit_cast(uint32_t, b) + 0x8000u;
#if __has_builtin(__builtin_amdgcn_perm)
    return __builtin_amdgcn_perm(ub, ua, 0x07060302u);   // {ub.hi16, ua.hi16}
#else
    return (ua >> 16) | (ub & 0xFFFF0000u);
#endif
}

// pack two floats to packed bf16 via compiler cvt path (m240: scalar-cast
// form lets the compiler fuse to v_cvt_pk_bf16_f32 -- 1 VALU op per pair
// vs 3 for the bit-trick pack). __hip_bfloat162 is not trivially copyable
// (has ctors), so move bits out with memcpy (register move, no cost).
__device__ __forceinline__ uint32_t pack_bf16_rn(float a, float b) {
    float2 f;
    f.x = a;
    f.y = b;
    __hip_bfloat162 h = __float22bfloat162_rn(f);
    uint32_t u;
    __builtin_memcpy(&u, &h, 4);
    return u;
}

// async global -> LDS, 16 B per lane; LDS dst = wave-uniform base + lane*16
__device__ __forceinline__ void gload16(const unsigned short* g, unsigned short* l) {
    __builtin_amdgcn_global_load_lds((const __attribute__((address_space(1))) void*)g,
                                     (__attribute__((address_space(3))) void*)l, 16, 0, 0);
}

// ---------------- fp32 -> bf16 convert (for W) ----------------
__global__ __launch_bounds__(256) void convert_kernel(const float* __restrict__ in,
                                                      unsigned short* __restrict__ out,
                                                      int n4) {
    int i = blockIdx.x * blockDim.x + threadIdx.x;
    if (i < n4) {
        float4 f = ((const float4*)in)[i];
        uint2 u;
        u.x = pack_bf16(f.x, f.y);
        u.y = pack_bf16(f.z, f.w);
        ((uint2*)out)[i] = u;
    }
}

// ---------------- K convert + V transpose, one pass ----------------
__global__ __launch_bounds__(256) void prep_kv(const float* __restrict__ k,
                                               const float* __restrict__ v,
                                               unsigned short* __restrict__ kb,
                                               unsigned short* __restrict__ vt) {
    __shared__ unsigned short tile[64][65];
    const int b = blockIdx.z, h = blockIdx.y, s0 = blockIdx.x * 64;
    const int r = threadIdx.x >> 2, cb = (threadIdx.x & 3) * 16;
    const size_t off = (size_t)(b * S + s0 + r) * E + h * Dh + cb;

    {   // K: convert in place (coalesced b128 out)
        const float* src = k + off;
        uint32_t o[8];
#pragma unroll
        for (int j = 0; j < 8; ++j) {
            float2 f = *(const float2*)(src + 2 * j);
            o[j] = pack_bf16(f.x, f.y);
        }
        unsigned short* dst = kb + off;
        *(uint4*)(dst) = *(const uint4*)(o);
        *(uint4*)(dst + 8) = *(const uint4*)(o + 4);
    }
    {   // V: transpose via LDS
        const float* src = v + off;
#pragma unroll
        for (int j = 0; j < 16; j += 4) {
            float4 f = *(const float4*)(src + j);
            tile[cb + j + 0][r] = f2bf(f.x);
            tile[cb + j + 1][r] = f2bf(f.y);
            tile[cb + j + 2][r] = f2bf(f.z);
            tile[cb + j + 3][r] = f2bf(f.w);
        }
    }
    __syncthreads();
    const int dv = threadIdx.x >> 2, seg = (threadIdx.x & 3) * 16;
    unsigned short* dst = vt + (((size_t)(b * H + h) * Dh + dv) * S + s0 + seg);
    *(uint4*)(dst) = *(const uint4*)(&tile[dv][seg]);
    *(uint4*)(dst + 8) = *(const uint4*)(&tile[dv][seg] + 8);
}

// ---------------- flash attention (R0 structure + setprio + cvt_pk) -------
// 64 q-rows per wave (256 q per block), 64-key double-buffered async-staged
// tiles. K/V fragments read from LDS ONCE per iter and reused by both
// q-halves. [R1: 32q/wave doubled LDS traffic -> LDS-pipe saturated, slower.
// R3: T15 PV-pipeline spilled to scratch, slower.]
// NEW vs R0: (a) s_setprio(1) around MFMA clusters (m191: +4-7% attn when
// co-resident blocks are phase-staggered); (b) softmax P-pack via
// v_cvt_pk_bf16_f32 path (1 op/pair vs 3).
constexpr int GSTR = 528;   // 8-row group stride in shorts
__global__ __launch_bounds__(256, 2) void attn_kernel(const float* __restrict__ q,
                                                      const unsigned short* __restrict__ kb,
                                                      const unsigned short* __restrict__ vt,
                                                      unsigned short* __restrict__ attn) {
    __shared__ unsigned short smem[18432];   // 36 KB: 2 x (K 4224 + V 4224); epilogue 4x64x72

    // XCD swizzle: the 8 q-blocks of one (b,h) share an XCD's L2
    const int wid = blockIdx.x + 8 * (blockIdx.y + 16 * blockIdx.z);
    const int c_ = wid & 7, j_ = wid >> 3;
    const int bh = c_ * 8 + (j_ >> 3), qblk = j_ & 7;
    const int b = bh >> 4, h = bh & 15;

    const int tid = threadIdx.x;
    const int wave = tid >> 6, lane = tid & 63;
    const int l32 = lane & 31, half = lane >> 5;
    const int x7 = l32 & 7, y4 = l32 >> 3;

    const int q0 = qblk * 256 + wave * 64;
    const float scl = 0.125f * 1.44269504088896f;   // D^-0.5 * log2(e)

    // Q in registers: qreg[qh][t][j] = Q[q = q0+qh*32+l32][d = 16t + half*8 + j]
    bf16x8 qreg[2][4];
#pragma unroll
    for (int qh = 0; qh < 2; ++qh) {
        const float* qsrc = q + ((size_t)(b * S + q0 + qh * 32 + l32)) * E + h * Dh + half * 8;
#pragma unroll
        for (int t = 0; t < 4; ++t) {
            float4 f0 = *(const float4*)(qsrc + 16 * t);
            float4 f1 = *(const float4*)(qsrc + 16 * t + 4);
            bf16x8 r;
            r[0] = (short)f2bf(f0.x * scl); r[1] = (short)f2bf(f0.y * scl);
            r[2] = (short)f2bf(f0.z * scl); r[3] = (short)f2bf(f0.w * scl);
            r[4] = (short)f2bf(f1.x * scl); r[5] = (short)f2bf(f1.y * scl);
            r[6] = (short)f2bf(f1.z * scl); r[7] = (short)f2bf(f1.w * scl);
            qreg[qh][t] = r;
        }
    }

    f32x16 fzero;
#pragma unroll
    for (int r = 0; r < 16; ++r) fzero[r] = 0.f;
    f32x16 oacc[2][2];
#pragma unroll
    for (int qh = 0; qh < 2; ++qh)
#pragma unroll
        for (int mt = 0; mt < 2; ++mt) oacc[qh][mt] = fzero;
    float lsum[2] = {0.f, 0.f};

    // staging: one gload16 covers 8 rows x 128 B; lane -> (row8 = lane>>3,
    // slot = lane&7); fetch granule sg = slot ^ row8
    const int row8 = lane >> 3;
    const int sg = (lane & 7) ^ row8;
    const unsigned short* kbase = kb + ((size_t)(b * S)) * E + h * Dh;
    const unsigned short* vtb = vt + ((size_t)(b * H + h) * Dh) * S;

    auto stage = [&](int kt, int bsel) {
        unsigned short* ksb = smem + bsel * 8448;
        unsigned short* vsb = ksb + 4224;
#pragma unroll
        for (int u = 0; u < 2; ++u) {
            const int gi = wave * 2 + u;
            gload16(kbase + (size_t)(kt * 64 + gi * 8 + row8) * E + sg * 8, ksb + gi * GSTR);
            gload16(vtb + (size_t)(gi * 8 + row8) * S + kt * 64 + sg * 8, vsb + gi * GSTR);
        }
    };

    // per-lane row offsets for fragment reads (row r = mt*32 + l32)
    int roff[2];
#pragma unroll
    for (int mt = 0; mt < 2; ++mt) roff[mt] = (mt * 4 + y4) * GSTR + x7 * 64;

    constexpr int NT = S / 64;   // 32
    stage(0, 0);

    for (int kt = 0; kt < NT; ++kt) {
        const int cur = kt & 1;
        __syncthreads();   // drains tile-kt loads (in flight one full iteration)
        if (kt + 1 < NT) stage(kt + 1, cur ^ 1);
        const unsigned short* ksb = smem + cur * 8448;
        const unsigned short* vsb = ksb + 4224;

        // K fragments once per iter (shared by both q-halves)
        bf16x8 kfrag[2][4];
#pragma unroll
        for (int mt = 0; mt < 2; ++mt)
#pragma unroll
            for (int t = 0; t < 4; ++t)
                kfrag[mt][t] = *(const bf16x8*)(ksb + roff[mt] + (((t * 2 + half) ^ x7) * 8));

        // S^T[key][q] both q-halves
        f32x16 st[2][2];
        __builtin_amdgcn_s_setprio(1);
#pragma unroll
        for (int qh = 0; qh < 2; ++qh)
#pragma unroll
            for (int mt = 0; mt < 2; ++mt) {
                st[qh][mt] = MFMA32(kfrag[mt][0], qreg[qh][0], fzero);
#pragma unroll
                for (int t = 1; t < 4; ++t)
                    st[qh][mt] = MFMA32(kfrag[mt][t], qreg[qh][t], st[qh][mt]);
            }
        __builtin_amdgcn_s_setprio(0);

        // p = exp2(s); pack key-pairs. reg r of tile mt: key = (r&3)+8*(r>>2)+4*half+32*mt
        uint32_t pkd[2][2][4][2];
#pragma unroll
        for (int qh = 0; qh < 2; ++qh) {
            float ls = 0.f;
#pragma unroll
            for (int mt = 0; mt < 2; ++mt)
#pragma unroll
                for (int g = 0; g < 4; ++g) {
                    float p0 = exp2_fast(st[qh][mt][4 * g + 0]);
                    float p1 = exp2_fast(st[qh][mt][4 * g + 1]);
                    float p2 = exp2_fast(st[qh][mt][4 * g + 2]);
                    float p3 = exp2_fast(st[qh][mt][4 * g + 3]);
                    ls += (p0 + p1) + (p2 + p3);
                    pkd[qh][mt][g][0] = pack_bf16_rn(p0, p1);
                    pkd[qh][mt][g][1] = pack_bf16_rn(p2, p3);
                }
            lsum[qh] += ls;
        }

        // V^T fragments once per iter
        bf16x8 vfrag[2][4];
#pragma unroll
        for (int mt = 0; mt < 2; ++mt)
#pragma unroll
            for (int c = 0; c < 4; ++c)
                vfrag[mt][c] = *(const bf16x8*)(vsb + roff[mt] + (((c * 2 + half) ^ x7) * 8));

        // O^T += V^T · P^T
#pragma unroll
        for (int qh = 0; qh < 2; ++qh)
#pragma unroll
            for (int c = 0; c < 4; ++c) {
                const int ms = c >> 1;
                const int g0 = 2 * (c & 1);
                uint32_t a0 = pkd[qh][ms][g0][0], a1 = pkd[qh][ms][g0][1];
                uint32_t b0 = pkd[qh][ms][g0 + 1][0], b1 = pkd[qh][ms][g0 + 1][1];
                uint32_t snd0 = half ? a0 : b0;
                uint32_t snd1 = half ? a1 : b1;
                uint32_t r0 = (uint32_t)__shfl_xor((int)snd0, 32);
                uint32_t r1 = (uint32_t)__shfl_xor((int)snd1, 32);
                int4 bi;
                bi.x = (int)(half ? r0 : a0);
                bi.y = (int)(half ? r1 : a1);
                bi.z = (int)(half ? b0 : r0);
                bi.w = (int)(half ? b1 : r1);
                bf16x8 bfrag = __builtin_bit_cast(bf16x8, bi);
                __builtin_amdgcn_s_setprio(1);
#pragma unroll
                for (int mt = 0; mt < 2; ++mt)
                    oacc[qh][mt] = MFMA32(vfrag[mt][c], bfrag, oacc[qh][mt]);
                __builtin_amdgcn_s_setprio(0);
            }
    }

    // row sums across key-halves, normalize, transpose via LDS, store
    __syncthreads();   // all LDS reads done before smem reuse
    float inv[2];
#pragma unroll
    for (int qh = 0; qh < 2; ++qh) {
        float l = lsum[qh] + (float)__shfl_xor(lsum[qh], 32);
        inv[qh] = 1.0f / l;
    }

    unsigned short* ob = smem + wave * (64 * 72);   // [qrow 0..63][dv 0..63] stride 72
#pragma unroll
    for (int qh = 0; qh < 2; ++qh)
#pragma unroll
        for (int mt = 0; mt < 2; ++mt)
#pragma unroll
            for (int g = 0; g < 4; ++g) {
                int dv0 = 8 * g + 4 * half + 32 * mt;
                uint2 w2;
                w2.x = pack_bf16_rn(oacc[qh][mt][4 * g + 0] * inv[qh],
                                    oacc[qh][mt][4 * g + 1] * inv[qh]);
                w2.y = pack_bf16_rn(oacc[qh][mt][4 * g + 2] * inv[qh],
                                    oacc[qh][mt][4 * g + 3] * inv[qh]);
                *(uint2*)(ob + (qh * 32 + l32) * 72 + dv0) = w2;
            }
    __syncthreads();
#pragma unroll
    for (int it = 0; it < 2; ++it) {
        int row = it * 32 + (lane >> 1);
        int seg = (lane & 1) * 32;
        unsigned short* gdst = attn + ((size_t)(b * S + q0 + row)) * E + h * Dh + seg;
#pragma unroll
        for (int j = 0; j < 4; ++j) {
            bf16x8 v8 = *(const bf16x8*)(ob + row * 72 + seg + j * 8);
            *(bf16x8*)(gdst + j * 8) = v8;
        }
    }
}

// ---------------- projection GEMM: C = A @ W^T + bias ----------------
// M=8192, N=1024, K=1024. BM=64, BN=128, BK=32 -> 1024 blocks = 4 blocks/CU
// (was 512 = 2/CU, grid-limited). 4 waves (2x2), each wave 32x64. gload_lds
// width-16 into LINEAR LDS tiles (rule 21), double-buffered, one barrier per
// K-step (stage(t+1) in flight a full iteration). XCD swizzle: each N-panel
// (W slice, 256 KB) pinned to one XCD's L2 (id&7 matches the HW %8
// round-robin per m157/m192). [R6 bug: grid was 128 not 1024 -> rows
// 1024..8191 never computed; fixed in launch below.]
__global__ __launch_bounds__(256) void proj_kernel(const unsigned short* __restrict__ A,
                                                   const unsigned short* __restrict__ W,
                                                   const float* __restrict__ bias,
                                                   float* __restrict__ C) {
    // 2 buffers x (As 64x32 = 2048 + Bs 128x32 = 4096 shorts) = 24 KB
    __shared__ unsigned short smem[12288];
    const int tid = threadIdx.x;
    const int wave = tid >> 6, lane = tid & 63, quad = lane >> 4, l16 = lane & 15;
    const int wm = wave >> 1, wn = wave & 1;
    const int id = blockIdx.x;
    const int n0 = (id & 7) * 128;     // XCD-pinned N-panel
    const int m0 = (id >> 3) * 64;

    f32x4 acc[2][4];
    f32x4 zero = {0.f, 0.f, 0.f, 0.f};
#pragma unroll
    for (int mi = 0; mi < 2; ++mi)
#pragma unroll
        for (int ni = 0; ni < 4; ++ni) acc[mi][ni] = zero;

    // staging: one gload16 per wave covers 16 rows x 64 B; lane ->
    // (row16 = lane>>2, slot = lane&3); LDS dst linear [16][32] shorts
    const int row16 = lane >> 2, slot = lane & 3;
    const unsigned short* Abase = A + (size_t)m0 * 1024;
    const unsigned short* Wbase = W + (size_t)n0 * 1024;

    auto stage = [&](int k0, int bsel) {
        unsigned short* as = smem + bsel * 6144;
        unsigned short* bs = as + 2048;
        // A: 64 rows = 4 groups of 16, wave w stages group w
        gload16(Abase + (size_t)(wave * 16 + row16) * 1024 + k0 + slot * 8, as + wave * 512);
        // B: 128 rows = 8 groups, wave w stages groups 2w, 2w+1
        gload16(Wbase + (size_t)(wave * 32 + row16) * 1024 + k0 + slot * 8, bs + wave * 1024);
        gload16(Wbase + (size_t)(wave * 32 + 16 + row16) * 1024 + k0 + slot * 8,
                bs + wave * 1024 + 512);
    };

    constexpr int NT = 1024 / 32;   // 32
    stage(0, 0);

    for (int t = 0; t < NT; ++t) {
        const int cur = t & 1;
        __syncthreads();   // drains stage(t) (issued one full iteration ago)
        if (t + 1 < NT) stage((t + 1) * 32, cur ^ 1);
        const unsigned short* as = smem + cur * 6144;
        const unsigned short* bs = as + 2048;

        bf16x8 af[2], bfr[4];
#pragma unroll
        for (int mi = 0; mi < 2; ++mi)
            af[mi] = *(const bf16x8*)(as + (wm * 32 + mi * 16 + l16) * 32 + quad * 8);
#pragma unroll
        for (int ni = 0; ni < 4; ++ni)
            bfr[ni] = *(const bf16x8*)(bs + (wn * 64 + ni * 16 + l16) * 32 + quad * 8);
#pragma unroll
        for (int mi = 0; mi < 2; ++mi)
#pragma unroll
            for (int ni = 0; ni < 4; ++ni)
                acc[mi][ni] = MFMA16(af[mi], bfr[ni], acc[mi][ni]);
    }

    float bb[4];
#pragma unroll
    for (int ni = 0; ni < 4; ++ni) bb[ni] = bias[n0 + wn * 64 + ni * 16 + l16];
#pragma unroll
    for (int mi = 0; mi < 2; ++mi) {
        const int row = m0 + wm * 32 + mi * 16 + quad * 4;
#pragma unroll
        for (int ni = 0; ni < 4; ++ni) {
            const int col = n0 + wn * 64 + ni * 16 + l16;
#pragma unroll
            for (int r = 0; r < 4; ++r)
                C[(size_t)(row + r) * 1024 + col] = acc[mi][ni][r] + bb[ni];
        }
    }
}

extern "C" void kernel_launch(void* const* d_in, const int* in_sizes, int n_in,
                              void* d_out, int out_size, void* d_ws, size_t ws_size,
                              hipStream_t stream) {
    const float* q = (const float*)d_in[0];
    const float* k = (const float*)d_in[1];
    const float* v = (const float*)d_in[2];
    const float* w = (const float*)d_in[3];
    const float* bias = (const float*)d_in[4];
    float* out = (float*)d_out;

    unsigned short* ws = (unsigned short*)d_ws;
    unsigned short* kb = ws;                       // BSE bf16
    unsigned short* vt = kb + BSE;                 // BSE bf16, layout [B,H,Dh,S]
    unsigned short* attnb = vt + BSE;              // BSE bf16
    unsigned short* wb = attnb + BSE;              // E*E bf16

    prep_kv<<<dim3(S / 64, H, Bz), dim3(256), 0, stream>>>(k, v, kb, vt);
    {
        int nw4 = (int)((size_t)E * E / 4);
        convert_kernel<<<dim3((nw4 + 255) / 256), dim3(256), 0, stream>>>(w, wb, nw4);
    }
    attn_kernel<<<dim3(S / 256, H, Bz), dim3(256), 0, stream>>>(q, kb, vt, attnb);
    // 128 m-blocks x 8 n-panels = 1024 blocks (R6 had 128: missing rows)
    proj_kernel<<<dim3((Bz * S) / 64 * 8, 1), dim3(256), 0, stream>>>(attnb, wb, bias, out);
}

// Round 8
// 252.209 us; speedup vs baseline: 1.0834x; 1.0834x over previous
//
#include <hip/hip_runtime.h>
#include <cstdint>
#include <cstddef>

typedef __attribute__((ext_vector_type(8))) short bf16x8;    // 8 bf16 = 4 VGPRs
typedef __attribute__((ext_vector_type(4))) float f32x4;
typedef __attribute__((ext_vector_type(16))) float f32x16;

#define MFMA16(a, b, c) __builtin_amdgcn_mfma_f32_16x16x32_bf16((a), (b), (c), 0, 0, 0)
#define MFMA32(a, b, c) __builtin_amdgcn_mfma_f32_32x32x16_bf16((a), (b), (c), 0, 0, 0)

constexpr int Bz = 4, S = 2048, E = 1024, H = 16, Dh = 64;
constexpr size_t BSE = (size_t)Bz * S * E;   // 8388608

__device__ __forceinline__ unsigned short f2bf(float f) {
    uint32_t u = __builtin_bit_cast(uint32_t, f);
    u += 0x7FFFu + ((u >> 16) & 1u);   // round-to-nearest-even
    return (unsigned short)(u >> 16);
}

__device__ __forceinline__ float exp2_fast(float x) {
#if __has_builtin(__builtin_amdgcn_exp2f)
    return __builtin_amdgcn_exp2f(x);
#else
    return exp2f(x);
#endif
}

// pack two floats to packed bf16 (round-half-up): 2 adds + 1 v_perm
__device__ __forceinline__ uint32_t pack_bf16(float a, float b) {
    uint32_t ua = __builtin_bit_cast(uint32_t, a) + 0x8000u;
    uint32_t ub = __builtin_bit_cast(uint32_t, b) + 0x8000u;
#if __has_builtin(__builtin_amdgcn_perm)
    return __builtin_amdgcn_perm(ub, ua, 0x07060302u);   // {ub.hi16, ua.hi16}
#else
    return (ua >> 16) | (ub & 0xFFFF0000u);
#endif
}

// async global -> LDS, 16 B per lane; LDS dst = wave-uniform base + lane*16
__device__ __forceinline__ void gload16(const unsigned short* g, unsigned short* l) {
    __builtin_amdgcn_global_load_lds((const __attribute__((address_space(1))) void*)g,
                                     (__attribute__((address_space(3))) void*)l, 16, 0, 0);
}

// ---------------- fp32 -> bf16 convert (for W) ----------------
__global__ __launch_bounds__(256) void convert_kernel(const float* __restrict__ in,
                                                      unsigned short* __restrict__ out,
                                                      int n4) {
    int i = blockIdx.x * blockDim.x + threadIdx.x;
    if (i < n4) {
        float4 f = ((const float4*)in)[i];
        uint2 u;
        u.x = pack_bf16(f.x, f.y);
        u.y = pack_bf16(f.z, f.w);
        ((uint2*)out)[i] = u;
    }
}

// ---------------- K convert + V transpose, one pass ----------------
__global__ __launch_bounds__(256) void prep_kv(const float* __restrict__ k,
                                               const float* __restrict__ v,
                                               unsigned short* __restrict__ kb,
                                               unsigned short* __restrict__ vt) {
    __shared__ unsigned short tile[64][65];
    const int b = blockIdx.z, h = blockIdx.y, s0 = blockIdx.x * 64;
    const int r = threadIdx.x >> 2, cb = (threadIdx.x & 3) * 16;
    const size_t off = (size_t)(b * S + s0 + r) * E + h * Dh + cb;

    {   // K: convert in place (coalesced b128 out)
        const float* src = k + off;
        uint32_t o[8];
#pragma unroll
        for (int j = 0; j < 8; ++j) {
            float2 f = *(const float2*)(src + 2 * j);
            o[j] = pack_bf16(f.x, f.y);
        }
        unsigned short* dst = kb + off;
        *(uint4*)(dst) = *(const uint4*)(o);
        *(uint4*)(dst + 8) = *(const uint4*)(o + 4);
    }
    {   // V: transpose via LDS
        const float* src = v + off;
#pragma unroll
        for (int j = 0; j < 16; j += 4) {
            float4 f = *(const float4*)(src + j);
            tile[cb + j + 0][r] = f2bf(f.x);
            tile[cb + j + 1][r] = f2bf(f.y);
            tile[cb + j + 2][r] = f2bf(f.z);
            tile[cb + j + 3][r] = f2bf(f.w);
        }
    }
    __syncthreads();
    const int dv = threadIdx.x >> 2, seg = (threadIdx.x & 3) * 16;
    unsigned short* dst = vt + (((size_t)(b * H + h) * Dh + dv) * S + s0 + seg);
    *(uint4*)(dst) = *(const uint4*)(&tile[dv][seg]);
    *(uint4*)(dst + 8) = *(const uint4*)(&tile[dv][seg] + 8);
}

// ---------------- flash attention (R0 known-good structure) ----------------
// 64 q-rows per wave (256 q per block), 64-key double-buffered async-staged
// tiles. K/V fragments read from LDS ONCE per iter and reused by both q-halves
// -> LDS reads per FLOP halved vs 32q/wave. Group-padded LDS: 8-row groups at
// stride 528 shorts (8 dwords mod 32 banks) + XOR slot swizzle -> row-aliased
// lanes hit different banks; within-group contiguous (global_load_lds-legal).
// [R1: 32q/wave 4blk/CU doubled LDS traffic -> LDS-pipe saturated, slower.
//  R3: T15 PV-pipeline spilled to scratch (WRITE_SIZE +10.7MB), slower.
//  R7: setprio around MFMA clusters + cvt_pk pack -> -4% (lockstep waves,
//  m190-consistent; SALU overhead). This plain form is the measured best.]
constexpr int GSTR = 528;   // 8-row group stride in shorts
__global__ __launch_bounds__(256, 2) void attn_kernel(const float* __restrict__ q,
                                                      const unsigned short* __restrict__ kb,
                                                      const unsigned short* __restrict__ vt,
                                                      unsigned short* __restrict__ attn) {
    __shared__ unsigned short smem[18432];   // 36 KB: 2 x (K 4224 + V 4224); epilogue 4x64x72

    // XCD swizzle: the 8 q-blocks of one (b,h) share an XCD's L2
    const int wid = blockIdx.x + 8 * (blockIdx.y + 16 * blockIdx.z);
    const int c_ = wid & 7, j_ = wid >> 3;
    const int bh = c_ * 8 + (j_ >> 3), qblk = j_ & 7;
    const int b = bh >> 4, h = bh & 15;

    const int tid = threadIdx.x;
    const int wave = tid >> 6, lane = tid & 63;
    const int l32 = lane & 31, half = lane >> 5;
    const int x7 = l32 & 7, y4 = l32 >> 3;

    const int q0 = qblk * 256 + wave * 64;
    const float scl = 0.125f * 1.44269504088896f;   // D^-0.5 * log2(e)

    // Q in registers: qreg[qh][t][j] = Q[q = q0+qh*32+l32][d = 16t + half*8 + j]
    bf16x8 qreg[2][4];
#pragma unroll
    for (int qh = 0; qh < 2; ++qh) {
        const float* qsrc = q + ((size_t)(b * S + q0 + qh * 32 + l32)) * E + h * Dh + half * 8;
#pragma unroll
        for (int t = 0; t < 4; ++t) {
            float4 f0 = *(const float4*)(qsrc + 16 * t);
            float4 f1 = *(const float4*)(qsrc + 16 * t + 4);
            bf16x8 r;
            r[0] = (short)f2bf(f0.x * scl); r[1] = (short)f2bf(f0.y * scl);
            r[2] = (short)f2bf(f0.z * scl); r[3] = (short)f2bf(f0.w * scl);
            r[4] = (short)f2bf(f1.x * scl); r[5] = (short)f2bf(f1.y * scl);
            r[6] = (short)f2bf(f1.z * scl); r[7] = (short)f2bf(f1.w * scl);
            qreg[qh][t] = r;
        }
    }

    f32x16 fzero;
#pragma unroll
    for (int r = 0; r < 16; ++r) fzero[r] = 0.f;
    f32x16 oacc[2][2];
#pragma unroll
    for (int qh = 0; qh < 2; ++qh)
#pragma unroll
        for (int mt = 0; mt < 2; ++mt) oacc[qh][mt] = fzero;
    float lsum[2] = {0.f, 0.f};

    // staging: one gload16 covers 8 rows x 128 B; lane -> (row8 = lane>>3,
    // slot = lane&7); fetch granule sg = slot ^ row8
    const int row8 = lane >> 3;
    const int sg = (lane & 7) ^ row8;
    const unsigned short* kbase = kb + ((size_t)(b * S)) * E + h * Dh;
    const unsigned short* vtb = vt + ((size_t)(b * H + h) * Dh) * S;

    auto stage = [&](int kt, int bsel) {
        unsigned short* ksb = smem + bsel * 8448;
        unsigned short* vsb = ksb + 4224;
#pragma unroll
        for (int u = 0; u < 2; ++u) {
            const int gi = wave * 2 + u;
            gload16(kbase + (size_t)(kt * 64 + gi * 8 + row8) * E + sg * 8, ksb + gi * GSTR);
            gload16(vtb + (size_t)(gi * 8 + row8) * S + kt * 64 + sg * 8, vsb + gi * GSTR);
        }
    };

    // per-lane row offsets for fragment reads (row r = mt*32 + l32)
    int roff[2];
#pragma unroll
    for (int mt = 0; mt < 2; ++mt) roff[mt] = (mt * 4 + y4) * GSTR + x7 * 64;

    constexpr int NT = S / 64;   // 32
    stage(0, 0);

    for (int kt = 0; kt < NT; ++kt) {
        const int cur = kt & 1;
        __syncthreads();   // drains tile-kt loads (in flight one full iteration)
        if (kt + 1 < NT) stage(kt + 1, cur ^ 1);
        const unsigned short* ksb = smem + cur * 8448;
        const unsigned short* vsb = ksb + 4224;

        // K fragments once per iter (shared by both q-halves)
        bf16x8 kfrag[2][4];
#pragma unroll
        for (int mt = 0; mt < 2; ++mt)
#pragma unroll
            for (int t = 0; t < 4; ++t)
                kfrag[mt][t] = *(const bf16x8*)(ksb + roff[mt] + (((t * 2 + half) ^ x7) * 8));

        // S^T[key][q] both q-halves
        f32x16 st[2][2];
#pragma unroll
        for (int qh = 0; qh < 2; ++qh)
#pragma unroll
            for (int mt = 0; mt < 2; ++mt) {
                st[qh][mt] = MFMA32(kfrag[mt][0], qreg[qh][0], fzero);
#pragma unroll
                for (int t = 1; t < 4; ++t)
                    st[qh][mt] = MFMA32(kfrag[mt][t], qreg[qh][t], st[qh][mt]);
            }

        // p = exp2(s); pack key-pairs. reg r of tile mt: key = (r&3)+8*(r>>2)+4*half+32*mt
        uint32_t pkd[2][2][4][2];
#pragma unroll
        for (int qh = 0; qh < 2; ++qh) {
            float ls = 0.f;
#pragma unroll
            for (int mt = 0; mt < 2; ++mt)
#pragma unroll
                for (int g = 0; g < 4; ++g) {
                    float p0 = exp2_fast(st[qh][mt][4 * g + 0]);
                    float p1 = exp2_fast(st[qh][mt][4 * g + 1]);
                    float p2 = exp2_fast(st[qh][mt][4 * g + 2]);
                    float p3 = exp2_fast(st[qh][mt][4 * g + 3]);
                    ls += (p0 + p1) + (p2 + p3);
                    pkd[qh][mt][g][0] = pack_bf16(p0, p1);
                    pkd[qh][mt][g][1] = pack_bf16(p2, p3);
                }
            lsum[qh] += ls;
        }

        // V^T fragments once per iter
        bf16x8 vfrag[2][4];
#pragma unroll
        for (int mt = 0; mt < 2; ++mt)
#pragma unroll
            for (int c = 0; c < 4; ++c)
                vfrag[mt][c] = *(const bf16x8*)(vsb + roff[mt] + (((c * 2 + half) ^ x7) * 8));

        // O^T += V^T · P^T
#pragma unroll
        for (int qh = 0; qh < 2; ++qh)
#pragma unroll
            for (int c = 0; c < 4; ++c) {
                const int ms = c >> 1;
                const int g0 = 2 * (c & 1);
                uint32_t a0 = pkd[qh][ms][g0][0], a1 = pkd[qh][ms][g0][1];
                uint32_t b0 = pkd[qh][ms][g0 + 1][0], b1 = pkd[qh][ms][g0 + 1][1];
                uint32_t snd0 = half ? a0 : b0;
                uint32_t snd1 = half ? a1 : b1;
                uint32_t r0 = (uint32_t)__shfl_xor((int)snd0, 32);
                uint32_t r1 = (uint32_t)__shfl_xor((int)snd1, 32);
                int4 bi;
                bi.x = (int)(half ? r0 : a0);
                bi.y = (int)(half ? r1 : a1);
                bi.z = (int)(half ? b0 : r0);
                bi.w = (int)(half ? b1 : r1);
                bf16x8 bfrag = __builtin_bit_cast(bf16x8, bi);
#pragma unroll
                for (int mt = 0; mt < 2; ++mt)
                    oacc[qh][mt] = MFMA32(vfrag[mt][c], bfrag, oacc[qh][mt]);
            }
    }

    // row sums across key-halves, normalize, transpose via LDS, store
    __syncthreads();   // all LDS reads done before smem reuse
    float inv[2];
#pragma unroll
    for (int qh = 0; qh < 2; ++qh) {
        float l = lsum[qh] + (float)__shfl_xor(lsum[qh], 32);
        inv[qh] = 1.0f / l;
    }

    unsigned short* ob = smem + wave * (64 * 72);   // [qrow 0..63][dv 0..63] stride 72
#pragma unroll
    for (int qh = 0; qh < 2; ++qh)
#pragma unroll
        for (int mt = 0; mt < 2; ++mt)
#pragma unroll
            for (int g = 0; g < 4; ++g) {
                int dv0 = 8 * g + 4 * half + 32 * mt;
                uint2 w2;
                w2.x = pack_bf16(oacc[qh][mt][4 * g + 0] * inv[qh],
                                 oacc[qh][mt][4 * g + 1] * inv[qh]);
                w2.y = pack_bf16(oacc[qh][mt][4 * g + 2] * inv[qh],
                                 oacc[qh][mt][4 * g + 3] * inv[qh]);
                *(uint2*)(ob + (qh * 32 + l32) * 72 + dv0) = w2;
            }
    __syncthreads();
#pragma unroll
    for (int it = 0; it < 2; ++it) {
        int row = it * 32 + (lane >> 1);
        int seg = (lane & 1) * 32;
        unsigned short* gdst = attn + ((size_t)(b * S + q0 + row)) * E + h * Dh + seg;
#pragma unroll
        for (int j = 0; j < 4; ++j) {
            bf16x8 v8 = *(const bf16x8*)(ob + row * 72 + seg + j * 8);
            *(bf16x8*)(gdst + j * 8) = v8;
        }
    }
}

// ---------------- projection GEMM: C = A @ W^T + bias ----------------
// M=8192, N=1024, K=1024. BM=BN=128, BK=32; 4 waves (2x2), each wave 64x64.
// (m97-structure): global_load_lds width-16 staging into LINEAR [128][32]
// LDS tiles (gload_lds dst must be linear, rule 21 "neither side"),
// double-buffered with ONE barrier per K-step: stage(t+1) issued right after
// the barrier, a full iteration in flight before the next barrier drains it.
// [R7: BM=64 x 1024-block retile regressed ~16us -- W-panel traffic doubled,
//  MFMA-per-barrier halved; 2-phase critical path is stage+barrier (m233),
//  which more blocks/CU don't shorten. This 128x128 form is the best.]
__global__ __launch_bounds__(256) void proj_kernel(const unsigned short* __restrict__ A,
                                                   const unsigned short* __restrict__ W,
                                                   const float* __restrict__ bias,
                                                   float* __restrict__ C) {
    // 2 buffers x (As 128x32 + Bs 128x32) shorts = 32 KB
    __shared__ unsigned short smem[16384];
    const int tid = threadIdx.x;
    const int wave = tid >> 6, lane = tid & 63, quad = lane >> 4, l16 = lane & 15;
    const int wm = wave >> 1, wn = wave & 1;
    const int m0 = blockIdx.x * 128, n0 = blockIdx.y * 128;

    f32x4 acc[4][4];
    f32x4 zero = {0.f, 0.f, 0.f, 0.f};
#pragma unroll
    for (int mi = 0; mi < 4; ++mi)
#pragma unroll
        for (int ni = 0; ni < 4; ++ni) acc[mi][ni] = zero;

    // staging: one gload16 per wave covers 16 rows x 64 B of a [128][32] tile;
    // lane -> (row16 = lane>>2, slot = lane&3); LDS dst linear: base + lane*16
    const int row16 = lane >> 2, slot = lane & 3;
    const unsigned short* Abase = A + (size_t)m0 * 1024;
    const unsigned short* Wbase = W + (size_t)n0 * 1024;

    auto stage = [&](int k0, int bsel) {
        unsigned short* as = smem + bsel * 8192;
        unsigned short* bs = as + 4096;
#pragma unroll
        for (int i = 0; i < 2; ++i) {
            const int g = wave * 2 + i;                 // 16-row group 0..7
            const int r = g * 16 + row16;
            gload16(Abase + (size_t)r * 1024 + k0 + slot * 8, as + g * 512);
            gload16(Wbase + (size_t)r * 1024 + k0 + slot * 8, bs + g * 512);
        }
    };

    constexpr int NT = 1024 / 32;   // 32
    stage(0, 0);

    for (int t = 0; t < NT; ++t) {
        const int cur = t & 1;
        __syncthreads();   // drains stage(t) (issued one full iteration ago)
        if (t + 1 < NT) stage((t + 1) * 32, cur ^ 1);
        const unsigned short* as = smem + cur * 8192;
        const unsigned short* bs = as + 4096;

        bf16x8 af[4], bfr[4];
#pragma unroll
        for (int mi = 0; mi < 4; ++mi)
            af[mi] = *(const bf16x8*)(as + (wm * 64 + mi * 16 + l16) * 32 + quad * 8);
#pragma unroll
        for (int ni = 0; ni < 4; ++ni)
            bfr[ni] = *(const bf16x8*)(bs + (wn * 64 + ni * 16 + l16) * 32 + quad * 8);
#pragma unroll
        for (int mi = 0; mi < 4; ++mi)
#pragma unroll
            for (int ni = 0; ni < 4; ++ni)
                acc[mi][ni] = MFMA16(af[mi], bfr[ni], acc[mi][ni]);
    }

    float bb[4];
#pragma unroll
    for (int ni = 0; ni < 4; ++ni) bb[ni] = bias[n0 + wn * 64 + ni * 16 + l16];
#pragma unroll
    for (int mi = 0; mi < 4; ++mi) {
        const int row = m0 + wm * 64 + mi * 16 + quad * 4;
#pragma unroll
        for (int ni = 0; ni < 4; ++ni) {
            const int col = n0 + wn * 64 + ni * 16 + l16;
#pragma unroll
            for (int r = 0; r < 4; ++r)
                C[(size_t)(row + r) * 1024 + col] = acc[mi][ni][r] + bb[ni];
        }
    }
}

extern "C" void kernel_launch(void* const* d_in, const int* in_sizes, int n_in,
                              void* d_out, int out_size, void* d_ws, size_t ws_size,
                              hipStream_t stream) {
    const float* q = (const float*)d_in[0];
    const float* k = (const float*)d_in[1];
    const float* v = (const float*)d_in[2];
    const float* w = (const float*)d_in[3];
    const float* bias = (const float*)d_in[4];
    float* out = (float*)d_out;

    unsigned short* ws = (unsigned short*)d_ws;
    unsigned short* kb = ws;                       // BSE bf16
    unsigned short* vt = kb + BSE;                 // BSE bf16, layout [B,H,Dh,S]
    unsigned short* attnb = vt + BSE;              // BSE bf16
    unsigned short* wb = attnb + BSE;              // E*E bf16

    prep_kv<<<dim3(S / 64, H, Bz), dim3(256), 0, stream>>>(k, v, kb, vt);
    {
        int nw4 = (int)((size_t)E * E / 4);
        convert_kernel<<<dim3((nw4 + 255) / 256), dim3(256), 0, stream>>>(w, wb, nw4);
    }
    attn_kernel<<<dim3(S / 256, H, Bz), dim3(256), 0, stream>>>(q, kb, vt, attnb);
    proj_kernel<<<dim3((Bz * S) / 128, E / 128), dim3(256), 0, stream>>>(attnb, wb, bias, out);
}

// Round 10
// 250.643 us; speedup vs baseline: 1.0901x; 1.0062x over previous
//
#include <hip/hip_runtime.h>
#include <cstdint>
#include <cstddef>

typedef __attribute__((ext_vector_type(8))) short bf16x8;    // 8 bf16 = 4 VGPRs
typedef __attribute__((ext_vector_type(4))) float f32x4;
typedef __attribute__((ext_vector_type(16))) float f32x16;

#define MFMA16(a, b, c) __builtin_amdgcn_mfma_f32_16x16x32_bf16((a), (b), (c), 0, 0, 0)
#define MFMA32(a, b, c) __builtin_amdgcn_mfma_f32_32x32x16_bf16((a), (b), (c), 0, 0, 0)

constexpr int Bz = 4, S = 2048, E = 1024, H = 16, Dh = 64;
constexpr size_t BSE = (size_t)Bz * S * E;   // 8388608

__device__ __forceinline__ unsigned short f2bf(float f) {
    uint32_t u = __builtin_bit_cast(uint32_t, f);
    u += 0x7FFFu + ((u >> 16) & 1u);   // round-to-nearest-even
    return (unsigned short)(u >> 16);
}

__device__ __forceinline__ float exp2_fast(float x) {
#if __has_builtin(__builtin_amdgcn_exp2f)
    return __builtin_amdgcn_exp2f(x);
#else
    return exp2f(x);
#endif
}

// pack two floats to packed bf16 (round-half-up): 2 adds + 1 v_perm
__device__ __forceinline__ uint32_t pack_bf16(float a, float b) {
    uint32_t ua = __builtin_bit_cast(uint32_t, a) + 0x8000u;
    uint32_t ub = __builtin_bit_cast(uint32_t, b) + 0x8000u;
#if __has_builtin(__builtin_amdgcn_perm)
    return __builtin_amdgcn_perm(ub, ua, 0x07060302u);   // {ub.hi16, ua.hi16}
#else
    return (ua >> 16) | (ub & 0xFFFF0000u);
#endif
}

// async global -> LDS, 16 B per lane; LDS dst = wave-uniform base + lane*16
__device__ __forceinline__ void gload16(const unsigned short* g, unsigned short* l) {
    __builtin_amdgcn_global_load_lds((const __attribute__((address_space(1))) void*)g,
                                     (__attribute__((address_space(3))) void*)l, 16, 0, 0);
}

// ---------------- K convert + V transpose + W convert, one pass ----------------
// (convert_kernel fused in: 2048 blocks x 256 threads x 2 floats = E*E exactly;
//  saves one launch + kernel tail. Audited R9: gid bijective over 2048 blocks,
//  idx < E*E/2, pack order == old convert_kernel.)
// [R9: permlane32_swap P-exchange failed absmax 0.27 -- builtin return-pair
//  ordering unverified; reverted to shfl_xor. Fusion kept.]
__global__ __launch_bounds__(256) void prep_kv(const float* __restrict__ k,
                                               const float* __restrict__ v,
                                               const float* __restrict__ w,
                                               unsigned short* __restrict__ kb,
                                               unsigned short* __restrict__ vt,
                                               unsigned short* __restrict__ wb) {
    __shared__ unsigned short tile[64][65];
    const int b = blockIdx.z, h = blockIdx.y, s0 = blockIdx.x * 64;
    const int r = threadIdx.x >> 2, cb = (threadIdx.x & 3) * 16;
    const size_t off = (size_t)(b * S + s0 + r) * E + h * Dh + cb;

    {   // K: convert in place (coalesced b128 out), float4 loads
        const float* src = k + off;
        uint32_t o[8];
#pragma unroll
        for (int j = 0; j < 4; ++j) {
            float4 f = *(const float4*)(src + 4 * j);
            o[2 * j + 0] = pack_bf16(f.x, f.y);
            o[2 * j + 1] = pack_bf16(f.z, f.w);
        }
        unsigned short* dst = kb + off;
        *(uint4*)(dst) = *(const uint4*)(o);
        *(uint4*)(dst + 8) = *(const uint4*)(o + 4);
    }
    {   // V: transpose via LDS
        const float* src = v + off;
#pragma unroll
        for (int j = 0; j < 16; j += 4) {
            float4 f = *(const float4*)(src + j);
            tile[cb + j + 0][r] = f2bf(f.x);
            tile[cb + j + 1][r] = f2bf(f.y);
            tile[cb + j + 2][r] = f2bf(f.z);
            tile[cb + j + 3][r] = f2bf(f.w);
        }
    }
    {   // W: fused fp32 -> bf16 convert (independent of the tile path)
        const int gid = blockIdx.x + 32 * (blockIdx.y + 16 * blockIdx.z);
        const int idx = gid * 256 + threadIdx.x;            // < E*E/2 = 524288
        float2 f = *(const float2*)(w + 2 * (size_t)idx);
        ((uint32_t*)wb)[idx] = pack_bf16(f.x, f.y);
    }
    __syncthreads();
    const int dv = threadIdx.x >> 2, seg = (threadIdx.x & 3) * 16;
    unsigned short* dst = vt + (((size_t)(b * H + h) * Dh + dv) * S + s0 + seg);
    *(uint4*)(dst) = *(const uint4*)(&tile[dv][seg]);
    *(uint4*)(dst + 8) = *(const uint4*)(&tile[dv][seg] + 8);
}

// ---------------- flash attention (R0 known-good structure) ----------------
// 64 q-rows per wave (256 q per block), 64-key double-buffered async-staged
// tiles. K/V fragments read from LDS ONCE per iter, reused by both q-halves.
// [R1: 32q/wave 4blk/CU doubled LDS traffic -> LDS-pipe saturated, slower.
//  R3: T15 PV-pipeline spilled to scratch, slower.
//  R7: setprio + cvt_pk pack -> -4% (lockstep waves, m190-consistent).
//  R9: permlane32_swap exchange -> absmax fail (builtin ordering unverified);
//  shfl_xor + cndmask path below is the proven form.]
constexpr int GSTR = 528;   // 8-row group stride in shorts
__global__ __launch_bounds__(256, 2) void attn_kernel(const float* __restrict__ q,
                                                      const unsigned short* __restrict__ kb,
                                                      const unsigned short* __restrict__ vt,
                                                      unsigned short* __restrict__ attn) {
    __shared__ unsigned short smem[18432];   // 36 KB: 2 x (K 4224 + V 4224); epilogue 4x64x72

    // XCD swizzle: the 8 q-blocks of one (b,h) share an XCD's L2
    const int wid = blockIdx.x + 8 * (blockIdx.y + 16 * blockIdx.z);
    const int c_ = wid & 7, j_ = wid >> 3;
    const int bh = c_ * 8 + (j_ >> 3), qblk = j_ & 7;
    const int b = bh >> 4, h = bh & 15;

    const int tid = threadIdx.x;
    const int wave = tid >> 6, lane = tid & 63;
    const int l32 = lane & 31, half = lane >> 5;
    const int x7 = l32 & 7, y4 = l32 >> 3;

    const int q0 = qblk * 256 + wave * 64;
    const float scl = 0.125f * 1.44269504088896f;   // D^-0.5 * log2(e)

    // Q in registers: qreg[qh][t][j] = Q[q = q0+qh*32+l32][d = 16t + half*8 + j]
    bf16x8 qreg[2][4];
#pragma unroll
    for (int qh = 0; qh < 2; ++qh) {
        const float* qsrc = q + ((size_t)(b * S + q0 + qh * 32 + l32)) * E + h * Dh + half * 8;
#pragma unroll
        for (int t = 0; t < 4; ++t) {
            float4 f0 = *(const float4*)(qsrc + 16 * t);
            float4 f1 = *(const float4*)(qsrc + 16 * t + 4);
            bf16x8 r;
            r[0] = (short)f2bf(f0.x * scl); r[1] = (short)f2bf(f0.y * scl);
            r[2] = (short)f2bf(f0.z * scl); r[3] = (short)f2bf(f0.w * scl);
            r[4] = (short)f2bf(f1.x * scl); r[5] = (short)f2bf(f1.y * scl);
            r[6] = (short)f2bf(f1.z * scl); r[7] = (short)f2bf(f1.w * scl);
            qreg[qh][t] = r;
        }
    }

    f32x16 fzero;
#pragma unroll
    for (int r = 0; r < 16; ++r) fzero[r] = 0.f;
    f32x16 oacc[2][2];
#pragma unroll
    for (int qh = 0; qh < 2; ++qh)
#pragma unroll
        for (int mt = 0; mt < 2; ++mt) oacc[qh][mt] = fzero;
    float lsum[2] = {0.f, 0.f};

    // staging: one gload16 covers 8 rows x 128 B; lane -> (row8 = lane>>3,
    // slot = lane&7); fetch granule sg = slot ^ row8
    const int row8 = lane >> 3;
    const int sg = (lane & 7) ^ row8;
    const unsigned short* kbase = kb + ((size_t)(b * S)) * E + h * Dh;
    const unsigned short* vtb = vt + ((size_t)(b * H + h) * Dh) * S;

    auto stage = [&](int kt, int bsel) {
        unsigned short* ksb = smem + bsel * 8448;
        unsigned short* vsb = ksb + 4224;
#pragma unroll
        for (int u = 0; u < 2; ++u) {
            const int gi = wave * 2 + u;
            gload16(kbase + (size_t)(kt * 64 + gi * 8 + row8) * E + sg * 8, ksb + gi * GSTR);
            gload16(vtb + (size_t)(gi * 8 + row8) * S + kt * 64 + sg * 8, vsb + gi * GSTR);
        }
    };

    // per-lane row offsets for fragment reads (row r = mt*32 + l32)
    int roff[2];
#pragma unroll
    for (int mt = 0; mt < 2; ++mt) roff[mt] = (mt * 4 + y4) * GSTR + x7 * 64;

    constexpr int NT = S / 64;   // 32
    stage(0, 0);

    for (int kt = 0; kt < NT; ++kt) {
        const int cur = kt & 1;
        __syncthreads();   // drains tile-kt loads (in flight one full iteration)
        if (kt + 1 < NT) stage(kt + 1, cur ^ 1);
        const unsigned short* ksb = smem + cur * 8448;
        const unsigned short* vsb = ksb + 4224;

        // K fragments once per iter (shared by both q-halves)
        bf16x8 kfrag[2][4];
#pragma unroll
        for (int mt = 0; mt < 2; ++mt)
#pragma unroll
            for (int t = 0; t < 4; ++t)
                kfrag[mt][t] = *(const bf16x8*)(ksb + roff[mt] + (((t * 2 + half) ^ x7) * 8));

        // S^T[key][q] both q-halves
        f32x16 st[2][2];
#pragma unroll
        for (int qh = 0; qh < 2; ++qh)
#pragma unroll
            for (int mt = 0; mt < 2; ++mt) {
                st[qh][mt] = MFMA32(kfrag[mt][0], qreg[qh][0], fzero);
#pragma unroll
                for (int t = 1; t < 4; ++t)
                    st[qh][mt] = MFMA32(kfrag[mt][t], qreg[qh][t], st[qh][mt]);
            }

        // p = exp2(s); pack key-pairs. reg r of tile mt: key = (r&3)+8*(r>>2)+4*half+32*mt
        uint32_t pkd[2][2][4][2];
#pragma unroll
        for (int qh = 0; qh < 2; ++qh) {
            float ls = 0.f;
#pragma unroll
            for (int mt = 0; mt < 2; ++mt)
#pragma unroll
                for (int g = 0; g < 4; ++g) {
                    float p0 = exp2_fast(st[qh][mt][4 * g + 0]);
                    float p1 = exp2_fast(st[qh][mt][4 * g + 1]);
                    float p2 = exp2_fast(st[qh][mt][4 * g + 2]);
                    float p3 = exp2_fast(st[qh][mt][4 * g + 3]);
                    ls += (p0 + p1) + (p2 + p3);
                    pkd[qh][mt][g][0] = pack_bf16(p0, p1);
                    pkd[qh][mt][g][1] = pack_bf16(p2, p3);
                }
            lsum[qh] += ls;
        }

        // V^T fragments once per iter
        bf16x8 vfrag[2][4];
#pragma unroll
        for (int mt = 0; mt < 2; ++mt)
#pragma unroll
            for (int c = 0; c < 4; ++c)
                vfrag[mt][c] = *(const bf16x8*)(vsb + roff[mt] + (((c * 2 + half) ^ x7) * 8));

        // O^T += V^T · P^T
#pragma unroll
        for (int qh = 0; qh < 2; ++qh)
#pragma unroll
            for (int c = 0; c < 4; ++c) {
                const int ms = c >> 1;
                const int g0 = 2 * (c & 1);
                uint32_t a0 = pkd[qh][ms][g0][0], a1 = pkd[qh][ms][g0][1];
                uint32_t b0 = pkd[qh][ms][g0 + 1][0], b1 = pkd[qh][ms][g0 + 1][1];
                uint32_t snd0 = half ? a0 : b0;
                uint32_t snd1 = half ? a1 : b1;
                uint32_t r0 = (uint32_t)__shfl_xor((int)snd0, 32);
                uint32_t r1 = (uint32_t)__shfl_xor((int)snd1, 32);
                int4 bi;
                bi.x = (int)(half ? r0 : a0);
                bi.y = (int)(half ? r1 : a1);
                bi.z = (int)(half ? b0 : r0);
                bi.w = (int)(half ? b1 : r1);
                bf16x8 bfrag = __builtin_bit_cast(bf16x8, bi);
#pragma unroll
                for (int mt = 0; mt < 2; ++mt)
                    oacc[qh][mt] = MFMA32(vfrag[mt][c], bfrag, oacc[qh][mt]);
            }
    }

    // row sums across key-halves, normalize, transpose via LDS, store
    __syncthreads();   // all LDS reads done before smem reuse
    float inv[2];
#pragma unroll
    for (int qh = 0; qh < 2; ++qh) {
        float l = lsum[qh] + (float)__shfl_xor(lsum[qh], 32);
        inv[qh] = 1.0f / l;
    }

    unsigned short* ob = smem + wave * (64 * 72);   // [qrow 0..63][dv 0..63] stride 72
#pragma unroll
    for (int qh = 0; qh < 2; ++qh)
#pragma unroll
        for (int mt = 0; mt < 2; ++mt)
#pragma unroll
            for (int g = 0; g < 4; ++g) {
                int dv0 = 8 * g + 4 * half + 32 * mt;
                uint2 w2;
                w2.x = pack_bf16(oacc[qh][mt][4 * g + 0] * inv[qh],
                                 oacc[qh][mt][4 * g + 1] * inv[qh]);
                w2.y = pack_bf16(oacc[qh][mt][4 * g + 2] * inv[qh],
                                 oacc[qh][mt][4 * g + 3] * inv[qh]);
                *(uint2*)(ob + (qh * 32 + l32) * 72 + dv0) = w2;
            }
    __syncthreads();
#pragma unroll
    for (int it = 0; it < 2; ++it) {
        int row = it * 32 + (lane >> 1);
        int seg = (lane & 1) * 32;
        unsigned short* gdst = attn + ((size_t)(b * S + q0 + row)) * E + h * Dh + seg;
#pragma unroll
        for (int j = 0; j < 4; ++j) {
            bf16x8 v8 = *(const bf16x8*)(ob + row * 72 + seg + j * 8);
            *(bf16x8*)(gdst + j * 8) = v8;
        }
    }
}

// ---------------- projection GEMM: C = A @ W^T + bias ----------------
// M=8192, N=1024, K=1024. BM=BN=128, BK=32; 4 waves (2x2), each wave 64x64.
// (m97-structure): global_load_lds width-16 staging into LINEAR [128][32]
// LDS tiles (gload_lds dst must be linear, rule 21 "neither side"),
// double-buffered with ONE barrier per K-step: stage(t+1) issued right after
// the barrier, a full iteration in flight before the next barrier drains it.
// [R7: BM=64 x 1024-block retile regressed ~16us -- W-panel traffic doubled,
//  MFMA-per-barrier halved; 2-phase critical path is stage+barrier (m233),
//  which more blocks/CU don't shorten. This 128x128 form is the best.]
__global__ __launch_bounds__(256) void proj_kernel(const unsigned short* __restrict__ A,
                                                   const unsigned short* __restrict__ W,
                                                   const float* __restrict__ bias,
                                                   float* __restrict__ C) {
    // 2 buffers x (As 128x32 + Bs 128x32) shorts = 32 KB
    __shared__ unsigned short smem[16384];
    const int tid = threadIdx.x;
    const int wave = tid >> 6, lane = tid & 63, quad = lane >> 4, l16 = lane & 15;
    const int wm = wave >> 1, wn = wave & 1;
    const int m0 = blockIdx.x * 128, n0 = blockIdx.y * 128;

    f32x4 acc[4][4];
    f32x4 zero = {0.f, 0.f, 0.f, 0.f};
#pragma unroll
    for (int mi = 0; mi < 4; ++mi)
#pragma unroll
        for (int ni = 0; ni < 4; ++ni) acc[mi][ni] = zero;

    // staging: one gload16 per wave covers 16 rows x 64 B of a [128][32] tile;
    // lane -> (row16 = lane>>2, slot = lane&3); LDS dst linear: base + lane*16
    const int row16 = lane >> 2, slot = lane & 3;
    const unsigned short* Abase = A + (size_t)m0 * 1024;
    const unsigned short* Wbase = W + (size_t)n0 * 1024;

    auto stage = [&](int k0, int bsel) {
        unsigned short* as = smem + bsel * 8192;
        unsigned short* bs = as + 4096;
#pragma unroll
        for (int i = 0; i < 2; ++i) {
            const int g = wave * 2 + i;                 // 16-row group 0..7
            const int r = g * 16 + row16;
            gload16(Abase + (size_t)r * 1024 + k0 + slot * 8, as + g * 512);
            gload16(Wbase + (size_t)r * 1024 + k0 + slot * 8, bs + g * 512);
        }
    };

    constexpr int NT = 1024 / 32;   // 32
    stage(0, 0);

    for (int t = 0; t < NT; ++t) {
        const int cur = t & 1;
        __syncthreads();   // drains stage(t) (issued one full iteration ago)
        if (t + 1 < NT) stage((t + 1) * 32, cur ^ 1);
        const unsigned short* as = smem + cur * 8192;
        const unsigned short* bs = as + 4096;

        bf16x8 af[4], bfr[4];
#pragma unroll
        for (int mi = 0; mi < 4; ++mi)
            af[mi] = *(const bf16x8*)(as + (wm * 64 + mi * 16 + l16) * 32 + quad * 8);
#pragma unroll
        for (int ni = 0; ni < 4; ++ni)
            bfr[ni] = *(const bf16x8*)(bs + (wn * 64 + ni * 16 + l16) * 32 + quad * 8);
#pragma unroll
        for (int mi = 0; mi < 4; ++mi)
#pragma unroll
            for (int ni = 0; ni < 4; ++ni)
                acc[mi][ni] = MFMA16(af[mi], bfr[ni], acc[mi][ni]);
    }

    float bb[4];
#pragma unroll
    for (int ni = 0; ni < 4; ++ni) bb[ni] = bias[n0 + wn * 64 + ni * 16 + l16];
#pragma unroll
    for (int mi = 0; mi < 4; ++mi) {
        const int row = m0 + wm * 64 + mi * 16 + quad * 4;
#pragma unroll
        for (int ni = 0; ni < 4; ++ni) {
            const int col = n0 + wn * 64 + ni * 16 + l16;
#pragma unroll
            for (int r = 0; r < 4; ++r)
                C[(size_t)(row + r) * 1024 + col] = acc[mi][ni][r] + bb[ni];
        }
    }
}

extern "C" void kernel_launch(void* const* d_in, const int* in_sizes, int n_in,
                              void* d_out, int out_size, void* d_ws, size_t ws_size,
                              hipStream_t stream) {
    const float* q = (const float*)d_in[0];
    const float* k = (const float*)d_in[1];
    const float* v = (const float*)d_in[2];
    const float* w = (const float*)d_in[3];
    const float* bias = (const float*)d_in[4];
    float* out = (float*)d_out;

    unsigned short* ws = (unsigned short*)d_ws;
    unsigned short* kb = ws;                       // BSE bf16
    unsigned short* vt = kb + BSE;                 // BSE bf16, layout [B,H,Dh,S]
    unsigned short* attnb = vt + BSE;              // BSE bf16
    unsigned short* wb = attnb + BSE;              // E*E bf16

    prep_kv<<<dim3(S / 64, H, Bz), dim3(256), 0, stream>>>(k, v, w, kb, vt, wb);
    attn_kernel<<<dim3(S / 256, H, Bz), dim3(256), 0, stream>>>(q, kb, vt, attnb);
    proj_kernel<<<dim3((Bz * S) / 128, E / 128), dim3(256), 0, stream>>>(attnb, wb, bias, out);
}